// Round 7
// baseline (287.872 us; speedup 1.0000x reference)
//
#include <hip/hip_runtime.h>
#include <math.h>

#define NB   8
#define SEQ  1024
#define CH   768
#define NH   12
#define HD   64
#define BHT  (NB * NH)    // 96
#define QKVN 2304         // 3*CH

typedef unsigned short u16;
typedef unsigned int   u32;
typedef __attribute__((ext_vector_type(8))) short bf16x8;  // 8 bf16 (4 VGPRs)
typedef __attribute__((ext_vector_type(4))) float f32x4;   // MFMA acc

__device__ __forceinline__ float bf2f(u32 s) {
    union { u32 u; float f; } v; v.u = s << 16; return v.f;
}
__device__ __forceinline__ u16 f2bf(float f) {
    union { float f; u32 u; } v; v.f = f;
    u32 u = v.u;
    return (u16)((u + 0x7fffu + ((u >> 16) & 1u)) >> 16);  // RNE, finite inputs
}
__device__ __forceinline__ float ld1(const u16* p) { return bf2f((u32)*p); }
__device__ __forceinline__ void st1(u16* p, float v) { *p = f2bf(v); }
__device__ __forceinline__ void st1(float* p, float v) { *p = v; }
__device__ __forceinline__ void st4v(u16* p, float a, float b, float c, float d) {
    ushort4 o; o.x = f2bf(a); o.y = f2bf(b); o.z = f2bf(c); o.w = f2bf(d);
    *(ushort4*)p = o;
}
__device__ __forceinline__ void st4v(float* p, float a, float b, float c, float d) {
    float4 o; o.x = a; o.y = b; o.z = c; o.w = d;
    *(float4*)p = o;
}
// async global->LDS, 16B per lane, dest = wave-uniform base + lane*16
__device__ __forceinline__ void gload16(const u16* g, u16* l) {
    __builtin_amdgcn_global_load_lds(
        (const __attribute__((address_space(1))) void*)g,
        (__attribute__((address_space(3))) void*)l, 16, 0, 0);
}

// ---------------------------------------------------------------------------
// dtype detect (proven): flag 1 = bf16 inputs, 0 = fp32 inputs
// ---------------------------------------------------------------------------
__global__ void detect_kernel(const u32* __restrict__ x, int* __restrict__ flag) {
    __shared__ int cnt;
    if (threadIdx.x == 0) cnt = 0;
    __syncthreads();
    int c = 0;
    for (int i = threadIdx.x; i < 2048; i += 256) {
        const u32 e0 = (x[i] >> 7) & 0xFFu;
        c += (e0 >= 110u && e0 <= 132u) ? 1 : 0;
    }
    atomicAdd(&cnt, c);
    __syncthreads();
    if (threadIdx.x == 0) *flag = (cnt > 1024) ? 1 : 0;
}

// ---------------------------------------------------------------------------
// Prep: inputs -> one contiguous bf16 arena in ws.
// ---------------------------------------------------------------------------
#define PREP_V4 5309184
__device__ __forceinline__ void prep_seg(size_t v, const size_t e0[6],
                                         int* segp, size_t* offp) {
    int seg = 5;
    if      (v < 1572864) seg = 0;
    else if (v < 2015232) seg = 1;
    else if (v < 2015808) seg = 2;
    else if (v < 5161536) seg = 3;
    else if (v < 5308992) seg = 4;
    *segp = seg; *offp = v * 4 - e0[seg];
}

__global__ __launch_bounds__(256) void prep_f32(
    const int* __restrict__ flag,
    const float* __restrict__ s0, const float* __restrict__ s1, const float* __restrict__ s2,
    const float* __restrict__ s3, const float* __restrict__ s4, const float* __restrict__ s5,
    u16* __restrict__ dst)
{
    if (*flag != 0) return;
    const float* const srcs[6] = {s0, s1, s2, s3, s4, s5};
    const size_t e0[6] = {0, 6291456, 8060928, 8063232, 20646144, 21235968};
    for (size_t v = blockIdx.x * 256 + threadIdx.x; v < PREP_V4; v += (size_t)gridDim.x * 256) {
        int seg; size_t off;
        prep_seg(v, e0, &seg, &off);
        const float4 f = *(const float4*)(srcs[seg] + off);
        ushort4 o; o.x = f2bf(f.x); o.y = f2bf(f.y); o.z = f2bf(f.z); o.w = f2bf(f.w);
        *(ushort4*)(dst + v * 4) = o;
    }
}

__global__ __launch_bounds__(256) void prep_bf16(
    const int* __restrict__ flag,
    const u16* __restrict__ s0, const u16* __restrict__ s1, const u16* __restrict__ s2,
    const u16* __restrict__ s3, const u16* __restrict__ s4, const u16* __restrict__ s5,
    u16* __restrict__ dst)
{
    if (*flag != 1) return;
    const u16* const srcs[6] = {s0, s1, s2, s3, s4, s5};
    const size_t e0[6] = {0, 6291456, 8060928, 8063232, 20646144, 21235968};
    for (size_t v = blockIdx.x * 256 + threadIdx.x; v < PREP_V4; v += (size_t)gridDim.x * 256) {
        int seg; size_t off;
        prep_seg(v, e0, &seg, &off);
        *(ushort4*)(dst + v * 4) = *(const ushort4*)(srcs[seg] + off);
    }
}

// ---------------------------------------------------------------------------
// 128x128 MFMA GEMM core, BK=64 (half the barriers of BK=32), gload16 staging.
// LDS [128 rows][64 u16] unpadded; 16B chunk at column c of row r holds global
// chunk (c + r) & 7 (source rotation -> even bank distribution on frag reads).
// SWAP=true computes C^T (n on (quad,reg), m on l15) for vectorized stores.
// ---------------------------------------------------------------------------
template<bool SWAP>
__device__ __forceinline__ void gemm128_core(
    const u16* __restrict__ Ag, const u16* __restrict__ Bg,   // tile row-0 bases
    f32x4 acc[4][4], u16* As, u16* Bs, int wm, int wn, int l15, int quad)
{
    const int t = threadIdx.x;
    const int w = t >> 6, lane = t & 63;
    const int ro = lane >> 3, ch = lane & 7;   // row-in-group, chunk
    const u16 *a_src[4], *b_src[4];
    u16 *lA[4], *lB[4];
#pragma unroll
    for (int i2 = 0; i2 < 4; i2++) {
        const int r = w * 32 + i2 * 8 + ro;
        const int g = (ch + r) & 7;
        a_src[i2] = Ag + (size_t)r * CH + g * 8;
        b_src[i2] = Bg + (size_t)r * CH + g * 8;
        lA[i2] = As + (w * 32 + i2 * 8) * 64;
        lB[i2] = Bs + (w * 32 + i2 * 8) * 64;
    }
#pragma unroll
    for (int mi = 0; mi < 4; mi++)
#pragma unroll
        for (int ni = 0; ni < 4; ni++) { f32x4 z = {0.f,0.f,0.f,0.f}; acc[mi][ni] = z; }

    for (int k0 = 0; k0 < CH; k0 += 64) {
        __syncthreads();                   // prev iter's frag reads done
#pragma unroll
        for (int i2 = 0; i2 < 4; i2++) {
            gload16(a_src[i2] + k0, lA[i2]);
            gload16(b_src[i2] + k0, lB[i2]);
        }
        __syncthreads();                   // drains vmcnt (loads landed)
#pragma unroll
        for (int kk = 0; kk < 2; kk++) {
            bf16x8 af[4], bfr[4];
#pragma unroll
            for (int mi = 0; mi < 4; mi++) {
                const int ra = wm * 64 + mi * 16 + l15;
                af[mi] = *(const bf16x8*)&As[ra * 64 + ((kk * 4 + quad - ra) & 7) * 8];
            }
#pragma unroll
            for (int ni = 0; ni < 4; ni++) {
                const int rb = wn * 64 + ni * 16 + l15;
                bfr[ni] = *(const bf16x8*)&Bs[rb * 64 + ((kk * 4 + quad - rb) & 7) * 8];
            }
#pragma unroll
            for (int mi = 0; mi < 4; mi++)
#pragma unroll
                for (int ni = 0; ni < 4; ni++)
                    acc[mi][ni] = SWAP
                        ? __builtin_amdgcn_mfma_f32_16x16x32_bf16(bfr[ni], af[mi], acc[mi][ni], 0, 0, 0)
                        : __builtin_amdgcn_mfma_f32_16x16x32_bf16(af[mi], bfr[ni], acc[mi][ni], 0, 0, 0);
        }
    }
}

// ---------------------------------------------------------------------------
// Kernel 1: QKV projection. grid (18,64), block 256.
// ---------------------------------------------------------------------------
__global__ __launch_bounds__(256) void qkv_gemm(
    const u16* __restrict__ x, const u16* __restrict__ w, const u16* __restrict__ bias,
    u16* __restrict__ Qn, u16* __restrict__ Kn, u16* __restrict__ Vt)
{
    __shared__ u16 As[128 * 64];
    __shared__ u16 Bs[128 * 64];
    const int t = threadIdx.x, lane = t & 63, wv = t >> 6;
    const int l15 = lane & 15, quad = lane >> 4;
    const int wm = wv >> 1, wn = wv & 1;
    const int m0 = blockIdx.y * 128, n0 = blockIdx.x * 128;
    const int which = n0 / CH;                 // 0=q 1=k 2=v (block-uniform)
    const int h     = ((n0 % CH) >> 6) + wn;   // wave-uniform
    const int b     = m0 >> 10;
    const size_t bh = (size_t)b * NH + h;
    const int sq0   = m0 & 1023;
    f32x4 acc[4][4];

    if (which == 2) {
        gemm128_core<false>(x + (size_t)m0 * CH, w + (size_t)n0 * CH,
                            acc, As, Bs, wm, wn, l15, quad);
        float bv[4];
#pragma unroll
        for (int ni = 0; ni < 4; ni++) bv[ni] = ld1(bias + n0 + wn * 64 + ni * 16 + l15);
#pragma unroll
        for (int mi = 0; mi < 4; mi++) {
            const int seq = sq0 + wm * 64 + mi * 16 + quad * 4;
#pragma unroll
            for (int ni = 0; ni < 4; ni++) {
                const int d = ni * 16 + l15;
                st4v(&Vt[(bh * HD + d) * SEQ + seq],
                     acc[mi][ni][0] + bv[ni], acc[mi][ni][1] + bv[ni],
                     acc[mi][ni][2] + bv[ni], acc[mi][ni][3] + bv[ni]);
            }
        }
    } else {
        gemm128_core<true>(x + (size_t)m0 * CH, w + (size_t)n0 * CH,
                           acc, As, Bs, wm, wn, l15, quad);
        u16* T2 = which ? Kn : Qn;
        const float qsc = which ? 1.0f : 0.125f;   // D^-0.5 folded into q
        float bvr[4][4];
#pragma unroll
        for (int ni = 0; ni < 4; ni++)
#pragma unroll
            for (int r = 0; r < 4; r++)
                bvr[ni][r] = ld1(bias + n0 + wn * 64 + ni * 16 + quad * 4 + r);
#pragma unroll
        for (int mi = 0; mi < 4; mi++) {
            const int seq = sq0 + wm * 64 + mi * 16 + l15;
#pragma unroll
            for (int ni = 0; ni < 4; ni++) {
                const int dbase = ni * 16 + quad * 4;
                st4v(&T2[(bh * SEQ + seq) * HD + dbase],
                     (acc[mi][ni][0] + bvr[ni][0]) * qsc,
                     (acc[mi][ni][1] + bvr[ni][1]) * qsc,
                     (acc[mi][ni][2] + bvr[ni][2]) * qsc,
                     (acc[mi][ni][3] + bvr[ni][3]) * qsc);
            }
        }
    }
}

// ---------------------------------------------------------------------------
// Kernel 2: MFMA attention. grid (8,96), block 256.
// QK uses SWAPPED operands (j on (quad,reg), i on l15): P writes are b64
// vectors, row-sums land on l15 (epilogue index), reduce = shfl over quads.
// K/V staged via gload16 into unpadded [64][64] tiles with chunk rotation.
// ---------------------------------------------------------------------------
__global__ __launch_bounds__(256) void attn_kernel(
    const u16* __restrict__ Qn, const u16* __restrict__ Kn, const u16* __restrict__ Vt,
    const u16* __restrict__ Ab, u16* __restrict__ AO)
{
    __shared__ u16 Ks[64 * 64];        // K tile [j][d], rotated chunks
    __shared__ u16 Vs[64 * 64];        // V tile [d][j], rotated chunks
    __shared__ u16 Ps[4 * 32 * 72];    // per-wave P [i][j], stride 72

    const int qb = blockIdx.x;
    const int y  = blockIdx.y;
    const int hh = y >> 3, b = y & 7;           // A-locality decode
    const size_t bh = (size_t)b * NH + hh;
    const int t  = threadIdx.x;
    const int w  = t >> 6, lane = t & 63;
    const int l15 = lane & 15, quad = lane >> 4;
    const int ro8 = lane >> 3, ch = lane & 7;   // staging row-in-group / chunk
    const int i0g = qb * 128 + w * 32;          // wave's first query (in-batch)
    u16* Psw = Ps + w * 32 * 72;

    // Q a-frags, loaded once (Qn pre-scaled by D^-0.5); used as B-operand.
    bf16x8 qa[2][2];
#pragma unroll
    for (int isub = 0; isub < 2; isub++)
#pragma unroll
        for (int db = 0; db < 2; db++)
            qa[isub][db] = *(const bf16x8*)(Qn +
                (bh * SEQ + i0g + isub * 16 + l15) * HD + db * 32 + quad * 8);

    f32x4 Op[2][4], Oa[2][4];
#pragma unroll
    for (int i = 0; i < 2; i++)
#pragma unroll
        for (int d = 0; d < 4; d++) { f32x4 z = {0.f,0.f,0.f,0.f}; Op[i][d] = z; Oa[i][d] = z; }
    float rl[2] = {0.f, 0.f};

    for (int kt = 0; kt < 16; kt++) {
        const int j0 = kt * 64;
        // A-operand prefetch (bf16 straight loads; latency overlaps staging+QK)
        bf16x8 afr[2][2];
#pragma unroll
        for (int jb = 0; jb < 2; jb++)
#pragma unroll
            for (int isub = 0; isub < 2; isub++)
                afr[jb][isub] = *(const bf16x8*)(Ab +
                    ((size_t)hh * SEQ + i0g + isub * 16 + l15) * SEQ
                    + j0 + jb * 32 + quad * 8);

        __syncthreads();                       // prev iter's K/V frag reads done
#pragma unroll
        for (int i2 = 0; i2 < 2; i2++) {
            const int r = w * 16 + i2 * 8 + ro8;
            const int g = (ch + r) & 7;
            gload16(Kn + (bh * SEQ + j0 + r) * HD + g * 8, Ks + (w * 16 + i2 * 8) * 64);
            gload16(Vt + (bh * HD + r) * SEQ + j0 + g * 8, Vs + (w * 16 + i2 * 8) * 64);
        }
        __syncthreads();                       // drains vmcnt

        // ---- QK^T swapped: s[r] for j = j16*16+quad*4+r, i = i0g+isub*16+l15
#pragma unroll
        for (int j16 = 0; j16 < 4; j16++) {
            const int jr = j16 * 16 + l15;
            const bf16x8 kf0 = *(const bf16x8*)&Ks[jr * 64 + ((    quad - jr) & 7) * 8];
            const bf16x8 kf1 = *(const bf16x8*)&Ks[jr * 64 + ((4 + quad - jr) & 7) * 8];
#pragma unroll
            for (int isub = 0; isub < 2; isub++) {
                f32x4 s = {0.f, 0.f, 0.f, 0.f};
                s = __builtin_amdgcn_mfma_f32_16x16x32_bf16(kf0, qa[isub][0], s, 0, 0, 0);
                s = __builtin_amdgcn_mfma_f32_16x16x32_bf16(kf1, qa[isub][1], s, 0, 0, 0);
                float p0 = __expf(fminf(s[0], 60.f));
                float p1 = __expf(fminf(s[1], 60.f));
                float p2 = __expf(fminf(s[2], 60.f));
                float p3 = __expf(fminf(s[3], 60.f));
                rl[isub] += (p0 + p1) + (p2 + p3);
                ushort4 o; o.x = f2bf(p0); o.y = f2bf(p1); o.z = f2bf(p2); o.w = f2bf(p3);
                *(ushort4*)&Psw[(isub * 16 + l15) * 72 + j16 * 16 + quad * 4] = o;
            }
        }

        // ---- PV + AV, swapped: D[d on (quad,r)][i on l15]
#pragma unroll
        for (int jb = 0; jb < 2; jb++) {
            bf16x8 pf[2];
#pragma unroll
            for (int isub = 0; isub < 2; isub++)
                pf[isub] = *(const bf16x8*)&Psw[(isub * 16 + l15) * 72 + jb * 32 + quad * 8];
#pragma unroll
            for (int d16 = 0; d16 < 4; d16++) {
                const int dr = d16 * 16 + l15;
                const bf16x8 vf = *(const bf16x8*)&Vs[dr * 64 + ((jb * 4 + quad - dr) & 7) * 8];
#pragma unroll
                for (int isub = 0; isub < 2; isub++) {
                    Op[isub][d16] = __builtin_amdgcn_mfma_f32_16x16x32_bf16(vf, pf[isub], Op[isub][d16], 0, 0, 0);
                    Oa[isub][d16] = __builtin_amdgcn_mfma_f32_16x16x32_bf16(vf, afr[jb][isub], Oa[isub][d16], 0, 0, 0);
                }
            }
        }
    }

    // ---- finalize: rl lives on (l15 = i); reduce over quads, vector store
    float inv[2];
#pragma unroll
    for (int isub = 0; isub < 2; isub++) {
        float v = rl[isub];
        v += __shfl_xor(v, 16);
        v += __shfl_xor(v, 32);
        inv[isub] = 1.f / v;
    }
#pragma unroll
    for (int isub = 0; isub < 2; isub++) {
        const int n = i0g + isub * 16 + l15;
#pragma unroll
        for (int d16 = 0; d16 < 4; d16++)
            st4v(&AO[((size_t)b * SEQ + n) * CH + hh * HD + d16 * 16 + quad * 4],
                 Op[isub][d16][0] * inv[isub] + Oa[isub][d16][0],
                 Op[isub][d16][1] * inv[isub] + Oa[isub][d16][1],
                 Op[isub][d16][2] * inv[isub] + Oa[isub][d16][2],
                 Op[isub][d16][3] * inv[isub] + Oa[isub][d16][3]);
    }
}

// ---------------------------------------------------------------------------
// Kernel 3: out = AO @ proj_w^T + proj_b. grid (6,64), block 256.
// ---------------------------------------------------------------------------
template<typename TO>
__global__ __launch_bounds__(256) void proj_gemm(
    const int* __restrict__ flag, const int want,
    const u16* __restrict__ AO, const u16* __restrict__ w, const u16* __restrict__ bias,
    TO* __restrict__ out)
{
    if (*flag != want) return;
    __shared__ u16 As[128 * 64];
    __shared__ u16 Bs[128 * 64];
    const int t = threadIdx.x, lane = t & 63, wv = t >> 6;
    const int l15 = lane & 15, quad = lane >> 4;
    const int wm = wv >> 1, wn = wv & 1;
    const int m0 = blockIdx.y * 128, n0 = blockIdx.x * 128;

    f32x4 acc[4][4];
    gemm128_core<true>(AO + (size_t)m0 * CH, w + (size_t)n0 * CH,
                       acc, As, Bs, wm, wn, l15, quad);

    float bvr[4][4];
#pragma unroll
    for (int ni = 0; ni < 4; ni++)
#pragma unroll
        for (int r = 0; r < 4; r++)
            bvr[ni][r] = ld1(bias + n0 + wn * 64 + ni * 16 + quad * 4 + r);
#pragma unroll
    for (int mi = 0; mi < 4; mi++) {
        const int m = m0 + wm * 64 + mi * 16 + l15;
#pragma unroll
        for (int ni = 0; ni < 4; ni++) {
            const int n = n0 + wn * 64 + ni * 16 + quad * 4;
            st4v(out + (size_t)m * CH + n,
                 acc[mi][ni][0] + bvr[ni][0], acc[mi][ni][1] + bvr[ni][1],
                 acc[mi][ni][2] + bvr[ni][2], acc[mi][ni][3] + bvr[ni][3]);
        }
    }
}

// ---------------------------------------------------------------------------
extern "C" void kernel_launch(void* const* d_in, const int* in_sizes, int n_in,
                              void* d_out, int out_size, void* d_ws, size_t ws_size,
                              hipStream_t stream) {
    (void)in_sizes; (void)n_in; (void)out_size; (void)ws_size;
    u16* ws = (u16*)d_ws;
    u16* xb   = ws;                 // 6,291,456
    u16* wqb  = ws + 6291456;       // 1,769,472
    u16* bqb  = ws + 8060928;       // 2,304
    u16* Ab   = ws + 8063232;       // 12,582,912
    u16* pwb  = ws + 20646144;      // 589,824
    u16* pbb  = ws + 21235968;      // 768
    u16* arena_end = ws + 21236736;
    const size_t S1 = (size_t)NB * NH * SEQ * HD;   // 6,291,456
    u16* Qn = arena_end;            // [BH][SEQ][D] bf16, pre-scaled
    u16* Kn = Qn + S1;              // [BH][SEQ][D]
    u16* Vt = Kn + S1;              // [BH][D][SEQ]
    u16* AO = Vt + S1;              // [B][SEQ][C]
    int* flag = (int*)(AO + S1);

    detect_kernel<<<dim3(1), dim3(256), 0, stream>>>((const u32*)d_in[0], flag);

    const dim3 blk(256);
    prep_f32 <<<dim3(4096), blk, 0, stream>>>(flag,
        (const float*)d_in[0], (const float*)d_in[1], (const float*)d_in[2],
        (const float*)d_in[3], (const float*)d_in[4], (const float*)d_in[5], ws);
    prep_bf16<<<dim3(4096), blk, 0, stream>>>(flag,
        (const u16*)d_in[0], (const u16*)d_in[1], (const u16*)d_in[2],
        (const u16*)d_in[3], (const u16*)d_in[4], (const u16*)d_in[5], ws);

    qkv_gemm<<<dim3(QKVN / 128, (NB * SEQ) / 128), blk, 0, stream>>>(
        xb, wqb, bqb, Qn, Kn, Vt);
    attn_kernel<<<dim3(SEQ / 128, BHT), blk, 0, stream>>>(Qn, Kn, Vt, Ab, AO);

    proj_gemm<float><<<dim3(CH / 128, (NB * SEQ) / 128), blk, 0, stream>>>(
        flag, 0, AO, pwb, pbb, (float*)d_out);
    proj_gemm<u16><<<dim3(CH / 128, (NB * SEQ) / 128), blk, 0, stream>>>(
        flag, 1, AO, pwb, pbb, (u16*)d_out);
}